// Round 4
// baseline (75.936 us; speedup 1.0000x reference)
//
#include <hip/hip_runtime.h>

// ToKmerLayer: one-hot conv1d + threshold == exact 3-mer match indicator.
// out[b,p,f] = 1.0 iff window code (base-4, MSB first) == code(feature f).
//
// R1 structure (best so far): barrier-free, LDS-free; per iteration each
// thread does 3 broadcast float4 loads (L1-resident, same addr within each
// 16-lane group), rebuilds the window code, and issues one coalesced 16 B
// store. This round's single A/B variable vs R1: PLAIN stores instead of
// __builtin_nontemporal_store -- testing whether nt's L2-bypass is the
// 5.0-vs-6.9 TB/s drain gap against the fillBuffer reference stream.

typedef float f32x4 __attribute__((ext_vector_type(4)));

constexpr int B = 64;
constexpr int L = 16384;
constexpr int F = 64;
constexpr int P = L - 2;              // 16382 output positions per row (k=3)
constexpr int T = 256;                // positions per block tile
constexpr int BPR = (P + T - 1) / T;  // 64 tiles per row

struct CodeTab { int c[64]; };        // feature -> code

__global__ __launch_bounds__(256) void kmer_kernel(
    const float* __restrict__ in,     // (B, L, 4) one-hot
    float* __restrict__ out,          // (B, P, F)
    CodeTab tab)
{
    const int tid = threadIdx.x;
    const int b   = blockIdx.x / BPR;
    const int p0  = (blockIdx.x % BPR) * T;
    const int q   = tid & 15;         // this thread's 4-feature slice

    // loop-invariant target codes for features 4q..4q+3
    const int c0 = tab.c[4 * q + 0];
    const int c1 = tab.c[4 * q + 1];
    const int c2 = tab.c[4 * q + 2];
    const int c3 = tab.c[4 * q + 3];

    const int nPos = min(T, P - p0);  // 256, or 254 in the last tile
    const f32x4* rowIn = reinterpret_cast<const f32x4*>(in) + (size_t)b * L;
    f32x4* outBase =
        reinterpret_cast<f32x4*>(out) + ((size_t)b * P + p0) * (F / 4);

    #pragma unroll 4
    for (int it = 0; it < 16; ++it) {
        const int i  = tid + 256 * it;   // chunk id within tile
        const int lp = i >> 4;           // local position
        const int lpc = lp < nPos ? lp : nPos - 1;  // clamp dead lanes
        const int p  = p0 + lpc;

        // window code from 3 one-hot vectors (values exactly 0.0/1.0)
        const f32x4 a0 = rowIn[p];
        const f32x4 a1 = rowIn[p + 1];
        const f32x4 a2 = rowIn[p + 2];
        const float d0 = fmaf(3.f, a0.w, fmaf(2.f, a0.z, a0.y));
        const float d1 = fmaf(3.f, a1.w, fmaf(2.f, a1.z, a1.y));
        const float d2 = fmaf(3.f, a2.w, fmaf(2.f, a2.z, a2.y));
        const int code = (int)fmaf(16.f, d0, fmaf(4.f, d1, d2));

        f32x4 v;
        v.x = (code == c0) ? 1.f : 0.f;
        v.y = (code == c1) ? 1.f : 0.f;
        v.z = (code == c2) ? 1.f : 0.f;
        v.w = (code == c3) ? 1.f : 0.f;
        if (lp < nPos)
            outBase[i] = v;              // plain store (A/B vs R1's nt)
    }
}

extern "C" void kernel_launch(void* const* d_in, const int* in_sizes, int n_in,
                              void* d_out, int out_size, void* d_ws, size_t ws_size,
                              hipStream_t stream) {
    const float* in = (const float*)d_in[0];
    // d_in[1] (one-hot kernel) and d_in[2] (k) are fixed by the reference's
    // deterministic build_kernel(3); the permutation is replicated here.
    float* out = (float*)d_out;

    // Replicate ToKmerLayer.build_kernel's deque ordering for k=3:
    // pair t (ascending-i order): appendleft(rc) -> index 31-t; append(i) -> 32+t.
    CodeTab tab;
    {
        bool seen[64] = {};
        int t = 0;
        for (int i = 0; i < 64; ++i) {
            const int d0 = (i >> 4) & 3, d1 = (i >> 2) & 3, d2 = i & 3;
            const int rc = ((3 - d2) << 4) | ((3 - d1) << 2) | (3 - d0);
            if (!seen[rc]) {
                seen[rc] = true;
                seen[i]  = true;
                tab.c[31 - t] = rc;   // reverse-complement kernel, appendleft
                tab.c[32 + t] = i;    // forward kernel, append
                ++t;
            }
        }
    }

    dim3 grid(B * BPR);  // 4096 blocks
    kmer_kernel<<<grid, 256, 0, stream>>>(in, out, tab);
}

// Round 5
// 60.759 us; speedup vs baseline: 1.2498x; 1.2498x over previous
//
#include <hip/hip_runtime.h>

// ToKmerLayer: one-hot conv1d + threshold == exact 3-mer match indicator.
// out[b,p,f] = 1.0 iff window code (base-4, MSB first) == code(feature f).
//
// Two-phase form. Phase 1 (~4 us): compute the 6-bit window code per
// position into d_ws (1 MB, uint8). Phase 2 (~dominant): pure store stream --
// per iteration one L1-resident broadcast ubyte load (a tile's 256 codes fit
// in ~4 cache lines) + 4 compares + one NT dwordx4 store. NT keeps the 268 MB
// write-once output out of L2 (R3 A/B: plain stores = 75.9 us vs NT 56.9).

typedef float f32x4 __attribute__((ext_vector_type(4)));

constexpr int B = 64;
constexpr int L = 16384;
constexpr int F = 64;
constexpr int P = L - 2;              // 16382 output positions per row (k=3)
constexpr int T = 256;                // positions per block tile
constexpr int BPR = (P + T - 1) / T;  // 64 tiles per row
constexpr int PADP = 16384;           // padded code-row stride in d_ws

struct CodeTab { int c[64]; };        // feature -> code

// ---- phase 1: codes[b*PADP + p] = 16*d[p] + 4*d[p+1] + d[p+2] ----
__global__ __launch_bounds__(256) void code_kernel(
    const float* __restrict__ in, unsigned char* __restrict__ codes)
{
    const int b = blockIdx.x >> 6;
    const int p = ((blockIdx.x & 63) << 8) + threadIdx.x;
    if (p >= P) return;
    const f32x4* rowIn = reinterpret_cast<const f32x4*>(in) + (size_t)b * L;
    const f32x4 a0 = rowIn[p];
    const f32x4 a1 = rowIn[p + 1];
    const f32x4 a2 = rowIn[p + 2];
    const float d0 = fmaf(3.f, a0.w, fmaf(2.f, a0.z, a0.y));
    const float d1 = fmaf(3.f, a1.w, fmaf(2.f, a1.z, a1.y));
    const float d2 = fmaf(3.f, a2.w, fmaf(2.f, a2.z, a2.y));
    codes[(size_t)b * PADP + p] =
        (unsigned char)(int)fmaf(16.f, d0, fmaf(4.f, d1, d2));
}

// ---- phase 2: fill-shaped NT store stream ----
__global__ __launch_bounds__(256) void store_kernel(
    const unsigned char* __restrict__ codes,
    float* __restrict__ out, CodeTab tab)
{
    const int tid = threadIdx.x;
    const int b   = blockIdx.x / BPR;
    const int p0  = (blockIdx.x % BPR) * T;
    const int q   = tid & 15;

    const int c0 = tab.c[4 * q + 0];
    const int c1 = tab.c[4 * q + 1];
    const int c2 = tab.c[4 * q + 2];
    const int c3 = tab.c[4 * q + 3];

    const int nPos = min(T, P - p0);  // 256, or 254 in the last tile
    const unsigned char* ctile = codes + (size_t)b * PADP + p0;
    f32x4* outBase =
        reinterpret_cast<f32x4*>(out) + ((size_t)b * P + p0) * (F / 4);

    #pragma unroll 4
    for (int it = 0; it < 16; ++it) {
        const int i  = tid + 256 * it;
        const int lp = i >> 4;
        const int lpc = lp < nPos ? lp : nPos - 1;
        const int code = ctile[lpc];     // L1-resident broadcast byte
        f32x4 v;
        v.x = (code == c0) ? 1.f : 0.f;
        v.y = (code == c1) ? 1.f : 0.f;
        v.z = (code == c2) ? 1.f : 0.f;
        v.w = (code == c3) ? 1.f : 0.f;
        if (lp < nPos)
            __builtin_nontemporal_store(v, outBase + i);
    }
}

// ---- R1 fallback (single kernel) in case ws is too small ----
__global__ __launch_bounds__(256) void kmer_fused_kernel(
    const float* __restrict__ in, float* __restrict__ out, CodeTab tab)
{
    const int tid = threadIdx.x;
    const int b   = blockIdx.x / BPR;
    const int p0  = (blockIdx.x % BPR) * T;
    const int q   = tid & 15;
    const int c0 = tab.c[4 * q + 0];
    const int c1 = tab.c[4 * q + 1];
    const int c2 = tab.c[4 * q + 2];
    const int c3 = tab.c[4 * q + 3];
    const int nPos = min(T, P - p0);
    const f32x4* rowIn = reinterpret_cast<const f32x4*>(in) + (size_t)b * L;
    f32x4* outBase =
        reinterpret_cast<f32x4*>(out) + ((size_t)b * P + p0) * (F / 4);
    #pragma unroll 4
    for (int it = 0; it < 16; ++it) {
        const int i  = tid + 256 * it;
        const int lp = i >> 4;
        const int lpc = lp < nPos ? lp : nPos - 1;
        const int p  = p0 + lpc;
        const f32x4 a0 = rowIn[p];
        const f32x4 a1 = rowIn[p + 1];
        const f32x4 a2 = rowIn[p + 2];
        const float d0 = fmaf(3.f, a0.w, fmaf(2.f, a0.z, a0.y));
        const float d1 = fmaf(3.f, a1.w, fmaf(2.f, a1.z, a1.y));
        const float d2 = fmaf(3.f, a2.w, fmaf(2.f, a2.z, a2.y));
        const int code = (int)fmaf(16.f, d0, fmaf(4.f, d1, d2));
        f32x4 v;
        v.x = (code == c0) ? 1.f : 0.f;
        v.y = (code == c1) ? 1.f : 0.f;
        v.z = (code == c2) ? 1.f : 0.f;
        v.w = (code == c3) ? 1.f : 0.f;
        if (lp < nPos)
            __builtin_nontemporal_store(v, outBase + i);
    }
}

extern "C" void kernel_launch(void* const* d_in, const int* in_sizes, int n_in,
                              void* d_out, int out_size, void* d_ws, size_t ws_size,
                              hipStream_t stream) {
    const float* in = (const float*)d_in[0];
    // d_in[1] (one-hot kernel) and d_in[2] (k) are fixed by the reference's
    // deterministic build_kernel(3); the permutation is replicated here.
    float* out = (float*)d_out;

    // Replicate ToKmerLayer.build_kernel's deque ordering for k=3:
    // pair t (ascending-i order): appendleft(rc) -> index 31-t; append(i) -> 32+t.
    CodeTab tab;
    {
        bool seen[64] = {};
        int t = 0;
        for (int i = 0; i < 64; ++i) {
            const int d0 = (i >> 4) & 3, d1 = (i >> 2) & 3, d2 = i & 3;
            const int rc = ((3 - d2) << 4) | ((3 - d1) << 2) | (3 - d0);
            if (!seen[rc]) {
                seen[rc] = true;
                seen[i]  = true;
                tab.c[31 - t] = rc;   // reverse-complement kernel, appendleft
                tab.c[32 + t] = i;    // forward kernel, append
                ++t;
            }
        }
    }

    const size_t codeBytes = (size_t)B * PADP;  // 1 MiB
    if (ws_size >= codeBytes) {
        unsigned char* codes = (unsigned char*)d_ws;
        code_kernel<<<dim3(B * 64), 256, 0, stream>>>(in, codes);
        store_kernel<<<dim3(B * BPR), 256, 0, stream>>>(codes, out, tab);
    } else {
        kmer_fused_kernel<<<dim3(B * BPR), 256, 0, stream>>>(in, out, tab);
    }
}

// Round 6
// 58.374 us; speedup vs baseline: 1.3008x; 1.0408x over previous
//
#include <hip/hip_runtime.h>

// ToKmerLayer: one-hot conv1d + threshold == exact 3-mer match indicator.
// out[b,p,f] = 1.0 iff window code (base-4, MSB first) == code(feature f).
//
// Two-phase, fill-shaped store sweep.
// Phase 1 (~3 us): 6-bit window code per position -> flat table codes[b*P+p]
// (1 MB uint8 in d_ws).
// Phase 2: EXACT fillBuffer shape -- 2048 blocks x 256 threads, flat chunk
// id c = t + 524288*it sweeps the dense (B*P*F) output sequentially; per
// iteration one L1-resident broadcast byte load + 4 cmp/sel + one NT
// dwordx4 store. No tiles, no predication in steady state (31 unguarded
// iters + 1 guarded). NT keeps the 268 MB write-once stream out of L2
// (R3 A/B: plain stores 75.9 us vs NT 56.9 us).

typedef float f32x4 __attribute__((ext_vector_type(4)));

constexpr int B = 64;
constexpr int L = 16384;
constexpr int F = 64;
constexpr int P = L - 2;                  // 16382 output positions per row
constexpr int NBLK  = 2048;               // phase-2 grid
constexpr int NTHR  = 256;
constexpr int STRIDE = NBLK * NTHR;       // 524288 chunks per sweep step
constexpr long long TOTAL = (long long)B * P * (F / 4);  // 16,775,168 chunks

struct CodeTab { int c[64]; };            // feature -> code

// ---- phase 1: codes[b*P + p] = 16*d[p] + 4*d[p+1] + d[p+2] ----
__global__ __launch_bounds__(256) void code_kernel(
    const float* __restrict__ in, unsigned char* __restrict__ codes)
{
    const int b = blockIdx.x >> 6;
    const int p = ((blockIdx.x & 63) << 8) + threadIdx.x;
    if (p >= P) return;
    const f32x4* rowIn = reinterpret_cast<const f32x4*>(in) + (size_t)b * L;
    const f32x4 a0 = rowIn[p];
    const f32x4 a1 = rowIn[p + 1];
    const f32x4 a2 = rowIn[p + 2];
    const float d0 = fmaf(3.f, a0.w, fmaf(2.f, a0.z, a0.y));
    const float d1 = fmaf(3.f, a1.w, fmaf(2.f, a1.z, a1.y));
    const float d2 = fmaf(3.f, a2.w, fmaf(2.f, a2.z, a2.y));
    codes[(size_t)b * P + p] =
        (unsigned char)(int)fmaf(16.f, d0, fmaf(4.f, d1, d2));
}

// ---- phase 2: flat sequential NT store sweep (fill-shaped) ----
__global__ __launch_bounds__(256) void store_flat_kernel(
    const unsigned char* __restrict__ codes,
    float* __restrict__ out, CodeTab tab)
{
    const int q  = threadIdx.x & 15;      // chunk c has (c & 15) == q always
    const int c0 = tab.c[4 * q + 0];
    const int c1 = tab.c[4 * q + 1];
    const int c2 = tab.c[4 * q + 2];
    const int c3 = tab.c[4 * q + 3];

    f32x4* outFlat = reinterpret_cast<f32x4*>(out);
    int c = threadIdx.x + blockIdx.x * NTHR;

    #pragma unroll 4
    for (int it = 0; it < 31; ++it) {     // all in-bounds: max c < TOTAL
        const int code = codes[c >> 4];
        f32x4 v;
        v.x = (code == c0) ? 1.f : 0.f;
        v.y = (code == c1) ? 1.f : 0.f;
        v.z = (code == c2) ? 1.f : 0.f;
        v.w = (code == c3) ? 1.f : 0.f;
        __builtin_nontemporal_store(v, outFlat + c);
        c += STRIDE;
    }
    if (c < TOTAL) {                      // 32nd step: guarded tail
        const int code = codes[c >> 4];
        f32x4 v;
        v.x = (code == c0) ? 1.f : 0.f;
        v.y = (code == c1) ? 1.f : 0.f;
        v.z = (code == c2) ? 1.f : 0.f;
        v.w = (code == c3) ? 1.f : 0.f;
        __builtin_nontemporal_store(v, outFlat + c);
    }
}

// ---- R1 fallback (single fused kernel) in case ws is too small ----
constexpr int T = 256;
constexpr int BPR = (P + T - 1) / T;
__global__ __launch_bounds__(256) void kmer_fused_kernel(
    const float* __restrict__ in, float* __restrict__ out, CodeTab tab)
{
    const int tid = threadIdx.x;
    const int b   = blockIdx.x / BPR;
    const int p0  = (blockIdx.x % BPR) * T;
    const int q   = tid & 15;
    const int c0 = tab.c[4 * q + 0];
    const int c1 = tab.c[4 * q + 1];
    const int c2 = tab.c[4 * q + 2];
    const int c3 = tab.c[4 * q + 3];
    const int nPos = min(T, P - p0);
    const f32x4* rowIn = reinterpret_cast<const f32x4*>(in) + (size_t)b * L;
    f32x4* outBase =
        reinterpret_cast<f32x4*>(out) + ((size_t)b * P + p0) * (F / 4);
    #pragma unroll 4
    for (int it = 0; it < 16; ++it) {
        const int i  = tid + 256 * it;
        const int lp = i >> 4;
        const int lpc = lp < nPos ? lp : nPos - 1;
        const int p  = p0 + lpc;
        const f32x4 a0 = rowIn[p];
        const f32x4 a1 = rowIn[p + 1];
        const f32x4 a2 = rowIn[p + 2];
        const float d0 = fmaf(3.f, a0.w, fmaf(2.f, a0.z, a0.y));
        const float d1 = fmaf(3.f, a1.w, fmaf(2.f, a1.z, a1.y));
        const float d2 = fmaf(3.f, a2.w, fmaf(2.f, a2.z, a2.y));
        const int code = (int)fmaf(16.f, d0, fmaf(4.f, d1, d2));
        f32x4 v;
        v.x = (code == c0) ? 1.f : 0.f;
        v.y = (code == c1) ? 1.f : 0.f;
        v.z = (code == c2) ? 1.f : 0.f;
        v.w = (code == c3) ? 1.f : 0.f;
        if (lp < nPos)
            __builtin_nontemporal_store(v, outBase + i);
    }
}

extern "C" void kernel_launch(void* const* d_in, const int* in_sizes, int n_in,
                              void* d_out, int out_size, void* d_ws, size_t ws_size,
                              hipStream_t stream) {
    const float* in = (const float*)d_in[0];
    // d_in[1] (one-hot kernel) and d_in[2] (k) are fixed by the reference's
    // deterministic build_kernel(3); the permutation is replicated here.
    float* out = (float*)d_out;

    // Replicate ToKmerLayer.build_kernel's deque ordering for k=3:
    // pair t (ascending-i order): appendleft(rc) -> index 31-t; append(i) -> 32+t.
    CodeTab tab;
    {
        bool seen[64] = {};
        int t = 0;
        for (int i = 0; i < 64; ++i) {
            const int d0 = (i >> 4) & 3, d1 = (i >> 2) & 3, d2 = i & 3;
            const int rc = ((3 - d2) << 4) | ((3 - d1) << 2) | (3 - d0);
            if (!seen[rc]) {
                seen[rc] = true;
                seen[i]  = true;
                tab.c[31 - t] = rc;   // reverse-complement kernel, appendleft
                tab.c[32 + t] = i;    // forward kernel, append
                ++t;
            }
        }
    }

    const size_t codeBytes = (size_t)B * P;   // ~1 MiB
    if (ws_size >= codeBytes) {
        unsigned char* codes = (unsigned char*)d_ws;
        code_kernel<<<dim3(B * 64), 256, 0, stream>>>(in, codes);
        store_flat_kernel<<<dim3(NBLK), NTHR, 0, stream>>>(codes, out, tab);
    } else {
        kmer_fused_kernel<<<dim3(B * BPR), 256, 0, stream>>>(in, out, tab);
    }
}

// Round 7
// 50.388 us; speedup vs baseline: 1.5070x; 1.1585x over previous
//
#include <hip/hip_runtime.h>

// ToKmerLayer: one-hot conv1d + threshold == exact 3-mer match indicator.
// out[b,p,f] = 1.0 iff window code (base-4, MSB first) == code(feature f).
//
// R6 A/B: identical to R5 (two-phase, fill-shaped flat store sweep) with ONE
// change -- plain stores instead of __builtin_nontemporal_store. Every NT
// variant (R1/R2/R4/R5) saturates at ~5.1 TB/s combined regardless of
// structure, while the co-run fillBuffer kernel sustains 6.87 TB/s with
// plain stores in exactly this flat-sweep shape. Testing whether the NT
// drain path is the cap.

typedef float f32x4 __attribute__((ext_vector_type(4)));

constexpr int B = 64;
constexpr int L = 16384;
constexpr int F = 64;
constexpr int P = L - 2;                  // 16382 output positions per row
constexpr int NBLK  = 2048;               // phase-2 grid
constexpr int NTHR  = 256;
constexpr int STRIDE = NBLK * NTHR;       // 524288 chunks per sweep step
constexpr long long TOTAL = (long long)B * P * (F / 4);  // 16,775,168 chunks

struct CodeTab { int c[64]; };            // feature -> code

// ---- phase 1: codes[b*P + p] = 16*d[p] + 4*d[p+1] + d[p+2] ----
__global__ __launch_bounds__(256) void code_kernel(
    const float* __restrict__ in, unsigned char* __restrict__ codes)
{
    const int b = blockIdx.x >> 6;
    const int p = ((blockIdx.x & 63) << 8) + threadIdx.x;
    if (p >= P) return;
    const f32x4* rowIn = reinterpret_cast<const f32x4*>(in) + (size_t)b * L;
    const f32x4 a0 = rowIn[p];
    const f32x4 a1 = rowIn[p + 1];
    const f32x4 a2 = rowIn[p + 2];
    const float d0 = fmaf(3.f, a0.w, fmaf(2.f, a0.z, a0.y));
    const float d1 = fmaf(3.f, a1.w, fmaf(2.f, a1.z, a1.y));
    const float d2 = fmaf(3.f, a2.w, fmaf(2.f, a2.z, a2.y));
    codes[(size_t)b * P + p] =
        (unsigned char)(int)fmaf(16.f, d0, fmaf(4.f, d1, d2));
}

// ---- phase 2: flat sequential PLAIN store sweep (fill-shaped) ----
__global__ __launch_bounds__(256) void store_flat_kernel(
    const unsigned char* __restrict__ codes,
    float* __restrict__ out, CodeTab tab)
{
    const int q  = threadIdx.x & 15;      // chunk c has (c & 15) == q always
    const int c0 = tab.c[4 * q + 0];
    const int c1 = tab.c[4 * q + 1];
    const int c2 = tab.c[4 * q + 2];
    const int c3 = tab.c[4 * q + 3];

    f32x4* outFlat = reinterpret_cast<f32x4*>(out);
    int c = threadIdx.x + blockIdx.x * NTHR;

    #pragma unroll 4
    for (int it = 0; it < 31; ++it) {     // all in-bounds: max c < TOTAL
        const int code = codes[c >> 4];
        f32x4 v;
        v.x = (code == c0) ? 1.f : 0.f;
        v.y = (code == c1) ? 1.f : 0.f;
        v.z = (code == c2) ? 1.f : 0.f;
        v.w = (code == c3) ? 1.f : 0.f;
        outFlat[c] = v;                   // plain store (A/B vs R5's nt)
        c += STRIDE;
    }
    if (c < TOTAL) {                      // 32nd step: guarded tail
        const int code = codes[c >> 4];
        f32x4 v;
        v.x = (code == c0) ? 1.f : 0.f;
        v.y = (code == c1) ? 1.f : 0.f;
        v.z = (code == c2) ? 1.f : 0.f;
        v.w = (code == c3) ? 1.f : 0.f;
        outFlat[c] = v;
    }
}

// ---- R1 fallback (single fused kernel) in case ws is too small ----
constexpr int T = 256;
constexpr int BPR = (P + T - 1) / T;
__global__ __launch_bounds__(256) void kmer_fused_kernel(
    const float* __restrict__ in, float* __restrict__ out, CodeTab tab)
{
    const int tid = threadIdx.x;
    const int b   = blockIdx.x / BPR;
    const int p0  = (blockIdx.x % BPR) * T;
    const int q   = tid & 15;
    const int c0 = tab.c[4 * q + 0];
    const int c1 = tab.c[4 * q + 1];
    const int c2 = tab.c[4 * q + 2];
    const int c3 = tab.c[4 * q + 3];
    const int nPos = min(T, P - p0);
    const f32x4* rowIn = reinterpret_cast<const f32x4*>(in) + (size_t)b * L;
    f32x4* outBase =
        reinterpret_cast<f32x4*>(out) + ((size_t)b * P + p0) * (F / 4);
    #pragma unroll 4
    for (int it = 0; it < 16; ++it) {
        const int i  = tid + 256 * it;
        const int lp = i >> 4;
        const int lpc = lp < nPos ? lp : nPos - 1;
        const int p  = p0 + lpc;
        const f32x4 a0 = rowIn[p];
        const f32x4 a1 = rowIn[p + 1];
        const f32x4 a2 = rowIn[p + 2];
        const float d0 = fmaf(3.f, a0.w, fmaf(2.f, a0.z, a0.y));
        const float d1 = fmaf(3.f, a1.w, fmaf(2.f, a1.z, a1.y));
        const float d2 = fmaf(3.f, a2.w, fmaf(2.f, a2.z, a2.y));
        const int code = (int)fmaf(16.f, d0, fmaf(4.f, d1, d2));
        f32x4 v;
        v.x = (code == c0) ? 1.f : 0.f;
        v.y = (code == c1) ? 1.f : 0.f;
        v.z = (code == c2) ? 1.f : 0.f;
        v.w = (code == c3) ? 1.f : 0.f;
        if (lp < nPos)
            __builtin_nontemporal_store(v, outBase + i);
    }
}

extern "C" void kernel_launch(void* const* d_in, const int* in_sizes, int n_in,
                              void* d_out, int out_size, void* d_ws, size_t ws_size,
                              hipStream_t stream) {
    const float* in = (const float*)d_in[0];
    // d_in[1] (one-hot kernel) and d_in[2] (k) are fixed by the reference's
    // deterministic build_kernel(3); the permutation is replicated here.
    float* out = (float*)d_out;

    // Replicate ToKmerLayer.build_kernel's deque ordering for k=3:
    // pair t (ascending-i order): appendleft(rc) -> index 31-t; append(i) -> 32+t.
    CodeTab tab;
    {
        bool seen[64] = {};
        int t = 0;
        for (int i = 0; i < 64; ++i) {
            const int d0 = (i >> 4) & 3, d1 = (i >> 2) & 3, d2 = i & 3;
            const int rc = ((3 - d2) << 4) | ((3 - d1) << 2) | (3 - d0);
            if (!seen[rc]) {
                seen[rc] = true;
                seen[i]  = true;
                tab.c[31 - t] = rc;   // reverse-complement kernel, appendleft
                tab.c[32 + t] = i;    // forward kernel, append
                ++t;
            }
        }
    }

    const size_t codeBytes = (size_t)B * P;   // ~1 MiB
    if (ws_size >= codeBytes) {
        unsigned char* codes = (unsigned char*)d_ws;
        code_kernel<<<dim3(B * 64), 256, 0, stream>>>(in, codes);
        store_flat_kernel<<<dim3(NBLK), NTHR, 0, stream>>>(codes, out, tab);
    } else {
        kmer_fused_kernel<<<dim3(B * BPR), 256, 0, stream>>>(in, out, tab);
    }
}

// Round 8
// 48.431 us; speedup vs baseline: 1.5679x; 1.0404x over previous
//
#include <hip/hip_runtime.h>

// ToKmerLayer: one-hot conv1d + threshold == exact 3-mer match indicator.
// out[b,p,f] = 1.0 iff window code (base-4, MSB first) == code(feature f).
//
// R7: single fused kernel in R6's proven fill shape (2048 blocks x 256
// threads, flat sequential PLAIN-store sweep -- R6 A/B: plain 50.4 us vs
// NT 58.4; sequential full-line plain stores get L2 write-combining).
// Block beta's 32 sweep iterations cover exactly the 512 positions
// beta*16 + (tid>>4) + it*32768, so a short prologue (2 positions/thread,
// 6 coalesced float4 loads, codes -> 2 KB LDS) replaces the separate
// phase-1 kernel, its launch gap, and the 2 MB code-table round trip.

typedef float f32x4 __attribute__((ext_vector_type(4)));

constexpr int B = 64;
constexpr int L = 16384;
constexpr int F = 64;
constexpr int P = L - 2;                  // 16382 output positions per row
constexpr int NBLK  = 2048;
constexpr int NTHR  = 256;
constexpr int STRIDE = NBLK * NTHR;       // 524288 chunks per sweep step
constexpr int NPOS_TOT = B * P;           // 1,048,448 positions
constexpr long long TOTAL = (long long)NPOS_TOT * (F / 4);  // 16,775,168 chunks

struct CodeTab { int c[64]; };            // feature -> code

__global__ __launch_bounds__(256) void kmer_flat_fused(
    const float* __restrict__ in,         // (B, L, 4) one-hot
    float* __restrict__ out,              // (B, P, F)
    CodeTab tab)
{
    __shared__ int codes[512];            // int (not byte): bank-broadcast reads

    const int tid  = threadIdx.x;
    const int beta = blockIdx.x;

    // --- prologue: compute this block's 512 window codes ---
    // slot s covers global position pi = beta*16 + (s&15) + (s>>4)*32768
    #pragma unroll
    for (int s = tid; s < 512; s += 256) {
        int pi = beta * 16 + (s & 15) + (s >> 4) * 32768;
        pi = pi < NPOS_TOT ? pi : NPOS_TOT - 1;   // clamp (guarded-tail slots)
        const int b = pi / P;                     // constant div -> mul_hi
        const int p = pi - b * P;                 // p <= P-1, loads p+2 <= L-1
        const f32x4* rowIn = reinterpret_cast<const f32x4*>(in) + (size_t)b * L;
        const f32x4 a0 = rowIn[p];
        const f32x4 a1 = rowIn[p + 1];
        const f32x4 a2 = rowIn[p + 2];
        const float d0 = fmaf(3.f, a0.w, fmaf(2.f, a0.z, a0.y));
        const float d1 = fmaf(3.f, a1.w, fmaf(2.f, a1.z, a1.y));
        const float d2 = fmaf(3.f, a2.w, fmaf(2.f, a2.z, a2.y));
        codes[s] = (int)fmaf(16.f, d0, fmaf(4.f, d1, d2));
    }
    __syncthreads();

    // --- R6's flat sequential plain-store sweep ---
    const int q  = tid & 15;              // chunk c has (c & 15) == q always
    const int c0 = tab.c[4 * q + 0];
    const int c1 = tab.c[4 * q + 1];
    const int c2 = tab.c[4 * q + 2];
    const int c3 = tab.c[4 * q + 3];
    const int g  = tid >> 4;              // position-group within block

    f32x4* outFlat = reinterpret_cast<f32x4*>(out);
    int c = tid + beta * NTHR;

    #pragma unroll 4
    for (int it = 0; it < 31; ++it) {     // all in-bounds: max c < TOTAL
        const int code = codes[it * 16 + g];
        f32x4 v;
        v.x = (code == c0) ? 1.f : 0.f;
        v.y = (code == c1) ? 1.f : 0.f;
        v.z = (code == c2) ? 1.f : 0.f;
        v.w = (code == c3) ? 1.f : 0.f;
        outFlat[c] = v;                   // plain store (R6 win)
        c += STRIDE;
    }
    if (c < TOTAL) {                      // 32nd step: guarded tail
        const int code = codes[31 * 16 + g];
        f32x4 v;
        v.x = (code == c0) ? 1.f : 0.f;
        v.y = (code == c1) ? 1.f : 0.f;
        v.z = (code == c2) ? 1.f : 0.f;
        v.w = (code == c3) ? 1.f : 0.f;
        outFlat[c] = v;
    }
}

extern "C" void kernel_launch(void* const* d_in, const int* in_sizes, int n_in,
                              void* d_out, int out_size, void* d_ws, size_t ws_size,
                              hipStream_t stream) {
    const float* in = (const float*)d_in[0];
    // d_in[1] (one-hot kernel) and d_in[2] (k) are fixed by the reference's
    // deterministic build_kernel(3); the permutation is replicated here.
    float* out = (float*)d_out;

    // Replicate ToKmerLayer.build_kernel's deque ordering for k=3:
    // pair t (ascending-i order): appendleft(rc) -> index 31-t; append(i) -> 32+t.
    CodeTab tab;
    {
        bool seen[64] = {};
        int t = 0;
        for (int i = 0; i < 64; ++i) {
            const int d0 = (i >> 4) & 3, d1 = (i >> 2) & 3, d2 = i & 3;
            const int rc = ((3 - d2) << 4) | ((3 - d1) << 2) | (3 - d0);
            if (!seen[rc]) {
                seen[rc] = true;
                seen[i]  = true;
                tab.c[31 - t] = rc;   // reverse-complement kernel, appendleft
                tab.c[32 + t] = i;    // forward kernel, append
                ++t;
            }
        }
    }

    kmer_flat_fused<<<dim3(NBLK), NTHR, 0, stream>>>(in, out, tab);
}